// Round 8
// baseline (221.066 us; speedup 1.0000x reference)
//
#include <hip/hip_runtime.h>
#include <math.h>

#define BATCH 8
#define CH    256
#define H     128
#define W     128
#define HW    (H * W)          // 16384
#define OH    65
#define OW    65
#define NPIX  (OH * OW)        // 4225

// ---------------- K1: channel L2 norms, pure stream ----------------
// 512 blocks (2/CU) x 256 thr (4 waves). Block = 256-pixel tile of one image;
// wave wv covers channels [wv*64, wv*64+64). Per channel the wave reads
// 1 KB contiguous; 64 independent loads/lane -> deep pipeline. Primes L3 with x.
__global__ __launch_bounds__(256) void norm_kernel(const float4* __restrict__ x4,
                                                   float* __restrict__ nrm) {
    const int b    = blockIdx.x >> 6;      // 0..7
    const int t    = blockIdx.x & 63;      // 256-px tile within image
    const int lane = threadIdx.x & 63;
    const int wv   = threadIdx.x >> 6;     // 0..3

    const float4* p = x4 + (size_t)(b * CH + wv * 64) * (HW / 4) + t * 64 + lane;
    float4 a = {0.f, 0.f, 0.f, 0.f};
    #pragma unroll 8
    for (int c = 0; c < 64; ++c) {
        float4 v = p[(size_t)c * (HW / 4)];
        a.x += v.x * v.x; a.y += v.y * v.y;
        a.z += v.z * v.z; a.w += v.w * v.w;
    }
    __shared__ float part[4][256];
    ((float4*)part[wv])[lane] = a;         // flat px index = 4*lane+comp
    __syncthreads();
    float s = part[0][threadIdx.x] + part[1][threadIdx.x]
            + part[2][threadIdx.x] + part[3][threadIdx.x];
    nrm[(size_t)b * HW + t * 256 + threadIdx.x] = sqrtf(s);
}

// ---------------- K2: softmax-weighted 3x3/s2 pool, float4 lanes ----------------
// Block = (b, 2-output-row tile oh0, channel-half cg): 8*33*2 = 528 blocks x 256
// thr (4 waves). Wave = 2 channels x 32 col-quads: lane l -> (h = l>>5 channel,
// j = l&31 owns cols 4j..4j+3). One float4 wave-load reads a full 512B row for 2
// channels. Reads 5 clamped rows (1.29x halo vs 1.52x at 1-row blocks).
// Decomposition per output row:  out[2j+1] = lane j alone (cols 4j..4j+2);
// out[2j] = T_j + S_{j-1} (T: col 4j; S from lane j-1: cols 4j-2,4j-1);
// out[0] = T_0 (OOB weights are zero);  out[64] = S_31.
#define OHT   33
#define K2TPB 256

__global__ __launch_bounds__(K2TPB) void pool_kernel(const float* __restrict__ x,
                                                     const float* __restrict__ nrm,
                                                     float* __restrict__ out) {
    const int b   = blockIdx.x & 7;        // XCD pin: image -> XCD
    const int rem = blockIdx.x >> 3;       // 0..65; consecutive rem = adjacent oh0
    const int ohT = rem < OHT ? rem : rem - OHT;
    const int cg  = rem < OHT ? 0 : 1;
    const int oh0 = ohT * 2;
    const bool hasB = (oh0 + 1) < OH;
    const int tid  = threadIdx.x;
    const int lane = tid & 63;
    const int wv   = tid >> 6;
    const int j    = lane & 31;
    const int h    = lane >> 5;

    // 5 clamped input rows: ih = 2*oh0 - 2 + r (A: r=0..2, B: r=2..4)
    int rowc[5];
    #pragma unroll
    for (int r = 0; r < 5; ++r) {
        int ih = oh0 * 2 - 2 + r;
        rowc[r] = ih < 0 ? 0 : (ih > H - 1 ? H - 1 : ih);
    }

    __shared__ float ns[5][W];        // 2.5 KB clamped norm rows
    __shared__ float wls[2 * OH][9];  // 4.6 KB weights: [0,65)=row A, [65,130)=B

    for (int id = tid; id < 5 * W; id += K2TPB) {
        int r = id >> 7, col = id & (W - 1);
        ns[r][col] = nrm[(size_t)b * HW + rowc[r] * W + col];
    }
    __syncthreads();

    // 130 softmax weight sets (verified math; OOB -> nv=0 in denom, wt=0 numer)
    if (tid < 2 * OH) {
        int ohl = tid >= OH ? 1 : 0;
        int ow  = tid - ohl * OH;
        int oh  = oh0 + ohl;
        if (oh < OH) {
            int iw0 = ow * 2 - 2;
            float nv[9]; bool val[9]; float m = 0.0f;
            #pragma unroll
            for (int kh = 0; kh < 3; ++kh) {
                int ih = oh * 2 + kh - 2;
                bool vh = (unsigned)ih < (unsigned)H;
                int rL = 2 * ohl + kh;
                #pragma unroll
                for (int kw = 0; kw < 3; ++kw) {
                    int iw = iw0 + kw;
                    int k  = kh * 3 + kw;
                    bool v = vh && ((unsigned)iw < (unsigned)W);
                    val[k] = v;
                    nv[k]  = v ? ns[rL][iw] : 0.0f;
                    m = fmaxf(m, nv[k]);
                }
            }
            float denom = 0.0f, wt[9];
            #pragma unroll
            for (int k = 0; k < 9; ++k) {
                float e = __expf(nv[k] - m);
                denom += e;
                wt[k] = val[k] ? e : 0.0f;
            }
            float inv = 1.0f / denom;
            #pragma unroll
            for (int k = 0; k < 9; ++k) wls[tid][k] = wt[k] * inv;
        }
    }
    __syncthreads();

    // per-lane weights, loaded once (rows 2j, 2j+1, 2j+2 <= 64; B adds +OH <= 129)
    const float tA0 = wls[2*j][2],   tA1 = wls[2*j][5],   tA2 = wls[2*j][8];
    const float oA0 = wls[2*j+1][0], oA1 = wls[2*j+1][1], oA2 = wls[2*j+1][2];
    const float oA3 = wls[2*j+1][3], oA4 = wls[2*j+1][4], oA5 = wls[2*j+1][5];
    const float oA6 = wls[2*j+1][6], oA7 = wls[2*j+1][7], oA8 = wls[2*j+1][8];
    const float sA0 = wls[2*j+2][0], sA1 = wls[2*j+2][1];
    const float sA2 = wls[2*j+2][3], sA3 = wls[2*j+2][4];
    const float sA4 = wls[2*j+2][6], sA5 = wls[2*j+2][7];
    const float tB0 = wls[OH+2*j][2],   tB1 = wls[OH+2*j][5],   tB2 = wls[OH+2*j][8];
    const float oB0 = wls[OH+2*j+1][0], oB1 = wls[OH+2*j+1][1], oB2 = wls[OH+2*j+1][2];
    const float oB3 = wls[OH+2*j+1][3], oB4 = wls[OH+2*j+1][4], oB5 = wls[OH+2*j+1][5];
    const float oB6 = wls[OH+2*j+1][6], oB7 = wls[OH+2*j+1][7], oB8 = wls[OH+2*j+1][8];
    const float sB0 = wls[OH+2*j+2][0], sB1 = wls[OH+2*j+2][1];
    const float sB2 = wls[OH+2*j+2][3], sB3 = wls[OH+2*j+2][4];
    const float sB4 = wls[OH+2*j+2][6], sB5 = wls[OH+2*j+2][7];

    const int cw = cg * 128 + wv * 32;           // wave's channel base
    const float* xl = x + (size_t)(b * CH + cw + h) * HW;
    float*       ol = out + (size_t)(b * CH + cw + h) * NPIX + (size_t)oh0 * OW;
    int boff[5];
    #pragma unroll
    for (int r = 0; r < 5; ++r) boff[r] = rowc[r] * W + 4 * j;

    #pragma unroll 4
    for (int c = 0; c < 16; ++c) {               // channel pair (cw+2c, cw+2c+1)
        const float* xc = xl + (size_t)(2 * c) * HW;
        float4 v0 = *(const float4*)(xc + boff[0]);
        float4 v1 = *(const float4*)(xc + boff[1]);
        float4 v2 = *(const float4*)(xc + boff[2]);
        float4 v3 = *(const float4*)(xc + boff[3]);
        float4 v4 = *(const float4*)(xc + boff[4]);
        float* oc = ol + (size_t)(2 * c) * NPIX;

        // row A (oh0): window rows v0,v1,v2
        float ownA = oA0*v0.x + oA1*v0.y + oA2*v0.z
                   + oA3*v1.x + oA4*v1.y + oA5*v1.z
                   + oA6*v2.x + oA7*v2.y + oA8*v2.z;      // -> out[2j+1]
        float TA = tA0*v0.x + tA1*v1.x + tA2*v2.x;        // -> out[2j] (col 4j)
        float SA = sA0*v0.z + sA1*v0.w + sA2*v1.z
                 + sA3*v1.w + sA4*v2.z + sA5*v2.w;        // -> out[2j+2]
        float SpA = __shfl_up(SA, 1);
        float resA = (j == 0) ? TA : TA + SpA;
        oc[2*j]     = resA;
        oc[2*j + 1] = ownA;
        if (j == 31) oc[64] = SA;                          // ow=64

        if (hasB) {
            // row B (oh0+1): window rows v2,v3,v4
            float ownB = oB0*v2.x + oB1*v2.y + oB2*v2.z
                       + oB3*v3.x + oB4*v3.y + oB5*v3.z
                       + oB6*v4.x + oB7*v4.y + oB8*v4.z;
            float TB = tB0*v2.x + tB1*v3.x + tB2*v4.x;
            float SB = sB0*v2.z + sB1*v2.w + sB2*v3.z
                     + sB3*v3.w + sB4*v4.z + sB5*v4.w;
            float SpB = __shfl_up(SB, 1);
            float resB = (j == 0) ? TB : TB + SpB;
            oc[OW + 2*j]     = resB;
            oc[OW + 2*j + 1] = ownB;
            if (j == 31) oc[OW + 64] = SB;
        }
    }
}

extern "C" void kernel_launch(void* const* d_in, const int* in_sizes, int n_in,
                              void* d_out, int out_size, void* d_ws, size_t ws_size,
                              hipStream_t stream) {
    const float* x = (const float*)d_in[0];
    float* out  = (float*)d_out;
    float* nbuf = (float*)d_ws;   // BATCH*H*W floats = 512 KB

    norm_kernel<<<512, 256, 0, stream>>>((const float4*)x, nbuf);
    // 8 images * 33 row-pairs * 2 channel-halves = 528 blocks
    pool_kernel<<<BATCH * OHT * 2, K2TPB, 0, stream>>>(x, nbuf, out);
}